// Round 2
// baseline (697.461 us; speedup 1.0000x reference)
//
#include <hip/hip_runtime.h>

#define DD 40

__global__ void k_init_deg(float* __restrict__ deg, int n) {
  int i = blockIdx.x * blockDim.x + threadIdx.x;
  if (i < n) deg[i] = 1.0f;  // self-loop contributes 1
}

__global__ void k_count_deg(const int* __restrict__ dst, float* __restrict__ deg, int E) {
  int i = blockIdx.x * blockDim.x + threadIdx.x;
  if (i < E) atomicAdd(&deg[dst[i]], 1.0f);
}

__global__ void k_rsqrt_inplace(float* __restrict__ deg, int n) {
  int i = blockIdx.x * blockDim.x + threadIdx.x;
  if (i < n) deg[i] = rsqrtf(deg[i]);  // deg >= 1 always (self-loop)
}

// agg[i] = dinv[node]^2 * x[i]; D=40 -> 10 float4 per node, row-aligned
__global__ void k_self_init(const float4* __restrict__ x4, const float* __restrict__ dinv,
                            float4* __restrict__ agg4, int n4 /* n*10 */) {
  int i = blockIdx.x * blockDim.x + threadIdx.x;
  if (i < n4) {
    int node = i / 10;
    float w = dinv[node];
    w *= w;
    float4 v = x4[i];
    v.x *= w; v.y *= w; v.z *= w; v.w *= w;
    agg4[i] = v;
  }
}

// One thread per (edge, feature) element: lane-contiguous within each 160B row.
__global__ void k_scatter(const float* __restrict__ x, const int* __restrict__ src,
                          const int* __restrict__ dst, const float* __restrict__ dinv,
                          float* __restrict__ agg, int total /* E*40 */) {
  int i = blockIdx.x * blockDim.x + threadIdx.x;
  int stride = blockDim.x * gridDim.x;
  for (; i < total; i += stride) {
    int e = i / DD;
    int d = i - e * DD;
    int s = src[e];
    int t = dst[e];
    float w = dinv[s] * dinv[t];
    atomicAdd(&agg[t * DD + d], w * x[s * DD + d]);
  }
}

// out[n*40+j] = (relu)(b[j] + sum_k in[n*40+k] * W[j*40+k]); thread per (n,j)
template <int RELU>
__global__ void k_linear(const float* __restrict__ in, const float* __restrict__ W,
                         const float* __restrict__ b, float* __restrict__ out,
                         int total /* n*40 */) {
  __shared__ float sW[DD * DD];
  __shared__ float sb[DD];
  for (int t = threadIdx.x; t < DD * DD; t += blockDim.x) sW[t] = W[t];
  if (threadIdx.x < DD) sb[threadIdx.x] = b[threadIdx.x];
  __syncthreads();
  int i = blockIdx.x * blockDim.x + threadIdx.x;
  if (i < total) {
    int node = i / DD;
    int j = i - node * DD;
    const float* row = in + node * DD;
    float acc = sb[j];
#pragma unroll
    for (int k = 0; k < DD; ++k) acc = fmaf(row[k], sW[j * DD + k], acc);
    if (RELU) acc = fmaxf(acc, 0.0f);
    out[i] = acc;
  }
}

// In-place linear: one node per thread, row held in registers -> no RAW hazard.
__global__ void k_linear_node_inplace(float* __restrict__ buf, const float* __restrict__ W,
                                      const float* __restrict__ b, int n) {
  __shared__ float sW[DD * DD];
  __shared__ float sb[DD];
  for (int t = threadIdx.x; t < DD * DD; t += blockDim.x) sW[t] = W[t];
  if (threadIdx.x < DD) sb[threadIdx.x] = b[threadIdx.x];
  __syncthreads();
  int node = blockIdx.x * blockDim.x + threadIdx.x;
  if (node < n) {
    float row[DD];
    float4* p4 = (float4*)(buf + node * DD);
#pragma unroll
    for (int q = 0; q < DD / 4; ++q) {
      float4 v = p4[q];
      row[4 * q + 0] = v.x; row[4 * q + 1] = v.y;
      row[4 * q + 2] = v.z; row[4 * q + 3] = v.w;
    }
    float outv[DD];
#pragma unroll
    for (int j = 0; j < DD; ++j) {
      float acc = sb[j];
#pragma unroll
      for (int k = 0; k < DD; ++k) acc = fmaf(row[k], sW[j * DD + k], acc);
      outv[j] = acc;
    }
#pragma unroll
    for (int q = 0; q < DD / 4; ++q) {
      p4[q] = make_float4(outv[4 * q], outv[4 * q + 1], outv[4 * q + 2], outv[4 * q + 3]);
    }
  }
}

extern "C" void kernel_launch(void* const* d_in, const int* in_sizes, int n_in,
                              void* d_out, int out_size, void* d_ws, size_t ws_size,
                              hipStream_t stream) {
  const float* x = (const float*)d_in[0];
  const int* ei = (const int*)d_in[1];  // harness pushes integer inputs as int32
  const float* W1 = (const float*)d_in[2];
  const float* b1 = (const float*)d_in[3];
  const float* W2 = (const float*)d_in[4];
  const float* b2 = (const float*)d_in[5];

  const int n = in_sizes[0] / DD;  // 100000
  const int E = in_sizes[1] / 2;   // 1600000
  const int* src = ei;
  const int* dst = ei + E;

  float* out = (float*)d_out;

  // Workspace layout: dinv [n] | h [n*DD]   (~16.4 MB)
  float* ws = (float*)d_ws;
  float* dinv = ws;
  float* h = ws + ((n + 255) & ~255);

  const int n4 = n * (DD / 4);
  const int totalE = E * DD;  // 64,000,000
  const int nD = n * DD;      // 4,000,000

  // Degrees (shared by both layers): deg -> rsqrt in place
  k_init_deg<<<(n + 255) / 256, 256, 0, stream>>>(dinv, n);
  k_count_deg<<<(E + 255) / 256, 256, 0, stream>>>(dst, dinv, E);
  k_rsqrt_inplace<<<(n + 255) / 256, 256, 0, stream>>>(dinv, n);

  // Layer 1: agg1 = Ahat @ x, built in d_out
  k_self_init<<<(n4 + 255) / 256, 256, 0, stream>>>((const float4*)x, dinv, (float4*)out, n4);
  k_scatter<<<8192, 256, 0, stream>>>(x, src, dst, dinv, out, totalE);
  // h = relu(agg1 @ W1^T + b1)
  k_linear<1><<<(nD + 255) / 256, 256, 0, stream>>>(out, W1, b1, h, nD);

  // Layer 2: agg2 = Ahat @ h, built in d_out (overwrites agg1)
  k_self_init<<<(n4 + 255) / 256, 256, 0, stream>>>((const float4*)h, dinv, (float4*)out, n4);
  k_scatter<<<8192, 256, 0, stream>>>(h, src, dst, dinv, out, totalE);
  // out = agg2 @ W2^T + b2, in place
  k_linear_node_inplace<<<(n + 255) / 256, 256, 0, stream>>>(out, W2, b2, n);
}